// Round 3
// baseline (10614.171 us; speedup 1.0000x reference)
//
#include <hip/hip_runtime.h>
#include <math.h>

// Problem constants (fixed by setup_inputs)
#define NQ   4096     // N source points
#define NK   4096     // M target points
#define DD   256      // feature dim (Ds == Dt)
#define NB   4        // batch
#define ROWS 64       // query rows per block
#define KT   512      // keys per tile (softmax-update granularity)
#define KS   32       // dims staged in LDS per slice
#define NTHR 512
#define QPITCH 260    // floats; 260 % 32 == 4
#define KPITCH 36     // floats; 36 % 32 == 4 -> bank-balanced b128 access

// ---------------------------------------------------------------------------
// Fused kernel: Q = f_src@W^T + b  (phase A, Q kept in LDS)
// then flash-style: S = Q@K^T, online softmax over 512-key tiles,
// pv += p * p_tgt, finally per-block partial sums of
// {sum p_src, sum p_corr, sum p_src x p_corr} atomically accumulated into
// out_acc[b*16 + 0..14].
//
// Inner loop: 8 rows x 8 keys per thread (64 fp32 accumulators) ->
// 16 ds_read_b128 per 256 FMAs: LDS port and VALU co-limiting (1.0 B/FMA).
// Swizzles: Qs column-XOR (chunk ^ row>>3), Ks pitch 36 (=4 mod 32) ->
// both read patterns cover all 32 banks in 8 distinct 16B windows, 8-lane
// broadcast each: structurally conflict-free.
// ---------------------------------------------------------------------------
__global__ __launch_bounds__(NTHR, 2)
void flash_kernel(const float* __restrict__ p_src,
                  const float* __restrict__ f_src,
                  const float* __restrict__ p_tgt,
                  const float* __restrict__ f_tgt,
                  const float* __restrict__ W,
                  const float* __restrict__ bias,
                  float* __restrict__ out_acc)
{
    __shared__ __align__(16) float Qs[ROWS][QPITCH];   // col-swizzled Q tile
    __shared__ __align__(16) float Ks[KT][KPITCH];     // one 32-dim K slice
    __shared__ float PTs[3][KT + 8];                   // p_tgt tile (transposed)
    __shared__ float wred[8][ROWS];                    // per-wave partials
    __shared__ float rowred[ROWS];                     // tile max / tile sum
    __shared__ float fred[8][8][24];                   // final pv partials
    __shared__ float lrun_s[ROWS];

    const int t    = threadIdx.x;
    const int lane = t & 63;
    const int wave = __builtin_amdgcn_readfirstlane(t >> 6);

    // Batch->XCD affinity swizzle (perf heuristic only; any mapping is
    // correct). Assuming dispatch round-robins linear wg across 8 XCDs,
    // b = (wg&7)>>1 pins each batch to one XCD pair, so each XCD's 4 MiB L2
    // holds only its own batch's 4 MB f_tgt panel.
    const int wg   = blockIdx.y * gridDim.x + blockIdx.x;   // 0..255
    const int b    = (wg & 7) >> 1;                          // 0..3
    const int rb   = (wg >> 3) + ((wg & 1) << 5);            // 0..63, bijective
    const int row0 = rb * ROWS;

    // slice s covers keys [(s>>3)*512, ...+512), dims [(s&7)*32, ...+32)
    // thread t stages key row t, all 32 dims (8 x float4).
    auto slice_src = [&](int s) {
        return f_tgt + ((size_t)b * NK + (s >> 3) * KT + t) * DD + (s & 7) * KS;
    };

    // Issue slice-0 K loads early: latency hides under Phase A compute.
    float4 v0[8];
    {
        const float* sp = slice_src(0);
        #pragma unroll
        for (int c = 0; c < 8; ++c) v0[c] = *(const float4*)(sp + 4 * c);
    }

    // ---------------- Phase A: Q tile = f_src @ W^T + bias ----------------
    {
        const int rbase = row0 + wave * 8;   // 8 rows per wave
        const int c0    = lane * 4;          // 4 output cols per thread
        float acc[8][4];
        #pragma unroll
        for (int i = 0; i < 8; ++i)
            #pragma unroll
            for (int j = 0; j < 4; ++j) acc[i][j] = 0.f;

        const float* fs = f_src + ((size_t)b * NQ + rbase) * DD;
        const float* Wp = W + (size_t)c0 * DD;
        for (int k = 0; k < DD; k += 4) {
            float4 w0 = *(const float4*)(Wp + 0 * DD + k);
            float4 w1 = *(const float4*)(Wp + 1 * DD + k);
            float4 w2 = *(const float4*)(Wp + 2 * DD + k);
            float4 w3 = *(const float4*)(Wp + 3 * DD + k);
            #pragma unroll
            for (int i = 0; i < 8; ++i) {
                float4 f = *(const float4*)(fs + i * DD + k);
                acc[i][0] += f.x*w0.x + f.y*w0.y + f.z*w0.z + f.w*w0.w;
                acc[i][1] += f.x*w1.x + f.y*w1.y + f.z*w1.z + f.w*w1.w;
                acc[i][2] += f.x*w2.x + f.y*w2.y + f.z*w2.z + f.w*w2.w;
                acc[i][3] += f.x*w3.x + f.y*w3.y + f.z*w3.z + f.w*w3.w;
            }
        }
        float4 bv = *(const float4*)(bias + c0);
        const int chunk = lane;                      // == c0 >> 2
        const int scol  = 4 * (chunk ^ (wave & 7));  // swizzle key = row>>3
        #pragma unroll
        for (int i = 0; i < 8; ++i) {
            float4 q;
            q.x = acc[i][0] + bv.x;  q.y = acc[i][1] + bv.y;
            q.z = acc[i][2] + bv.z;  q.w = acc[i][3] + bv.w;
            *(float4*)&Qs[wave * 8 + i][scol] = q;
        }
    }

    // ---------------- Prologue: write K slice 0 + PT tile 0 ----------------
    {
        #pragma unroll
        for (int c = 0; c < 8; ++c) *(float4*)&Ks[t][4 * c] = v0[c];
        const float* pp = p_tgt + ((size_t)b * NK + t) * 3;
        PTs[0][t] = pp[0]; PTs[1][t] = pp[1]; PTs[2][t] = pp[2];
    }
    __syncthreads();   // covers Qs writes + slice-0/PT staging

    // thread tiling for S: 8 rows (rg) x 8 keys (mg, strided by 64)
    const int rg = t & 7;     // row group: rows rg*8 + i
    const int mg = t >> 3;    // 0..63: keys mg + 64*j

    float m_run[8], l_run[8], pv[8][3];
    #pragma unroll
    for (int i = 0; i < 8; ++i) {
        m_run[i] = -INFINITY; l_run[i] = 0.f;
        pv[i][0] = pv[i][1] = pv[i][2] = 0.f;
    }
    float S[8][8];

    const int NSLICE = (NK / KT) * (DD / KS);   // 8 tiles x 8 slices = 64
    for (int s = 0; s < NSLICE; ++s) {
        // issue next-slice global loads early (latency hides under compute)
        float4 nv[8];
        float npt[3];
        const bool have_next = (s + 1) < NSLICE;
        if (have_next) {
            const float* sp = slice_src(s + 1);
            #pragma unroll
            for (int c = 0; c < 8; ++c) nv[c] = *(const float4*)(sp + 4 * c);
            if (((s + 1) & 7) == 0) {
                const float* pp = p_tgt +
                    ((size_t)b * NK + ((s + 1) >> 3) * KT + t) * 3;
                npt[0] = pp[0]; npt[1] = pp[1]; npt[2] = pp[2];
            }
        }

        if ((s & 7) == 0) {
            #pragma unroll
            for (int i = 0; i < 8; ++i)
                #pragma unroll
                for (int j = 0; j < 8; ++j) S[i][j] = 0.f;
        }

        // ---- 8x8 fp32 outer-product over this 32-dim slice ----
        #pragma unroll
        for (int kk = 0; kk < KS; kk += 4) {
            const int chunk = ((s & 7) * KS + kk) >> 2;   // global dim / 4
            const int qcol  = 4 * (chunk ^ rg);
            float4 kv[8];
            #pragma unroll
            for (int j = 0; j < 8; ++j)
                kv[j] = *(const float4*)&Ks[mg + 64 * j][kk];
            #pragma unroll
            for (int i = 0; i < 8; ++i) {
                const float4 q = *(const float4*)&Qs[rg * 8 + i][qcol];
                #pragma unroll
                for (int j = 0; j < 8; ++j) {
                    S[i][j] += q.x*kv[j].x + q.y*kv[j].y
                             + q.z*kv[j].z + q.w*kv[j].w;
                }
            }
        }

        // ---------------- tile boundary: online softmax update ----------------
        if ((s & 7) == 7) {
            // 1) row max: local -> within-wave (lanes sharing rg) -> cross-wave
            float mx[8];
            #pragma unroll
            for (int i = 0; i < 8; ++i) {
                float m0 = S[i][0];
                #pragma unroll
                for (int j = 1; j < 8; ++j) m0 = fmaxf(m0, S[i][j]);
                m0 = fmaxf(m0, __shfl_xor(m0, 8));
                m0 = fmaxf(m0, __shfl_xor(m0, 16));
                m0 = fmaxf(m0, __shfl_xor(m0, 32));
                mx[i] = m0;
            }
            if (lane < 8) {
                #pragma unroll
                for (int i = 0; i < 8; ++i) wred[wave][lane * 8 + i] = mx[i];
            }
            __syncthreads();
            if (t < ROWS) {
                float m0 = wred[0][t];
                #pragma unroll
                for (int w = 1; w < 8; ++w) m0 = fmaxf(m0, wred[w][t]);
                rowred[t] = m0;
            }
            __syncthreads();

            // 2) p = exp(S - mnew); pv update; row-sum reduce
            float pt[8][3];
            #pragma unroll
            for (int j = 0; j < 8; ++j)
                #pragma unroll
                for (int c = 0; c < 3; ++c)
                    pt[j][c] = PTs[c][mg + 64 * j];

            float psum[8], scale[8];
            #pragma unroll
            for (int i = 0; i < 8; ++i) {
                const int r = rg * 8 + i;
                const float mnew = fmaxf(m_run[i], rowred[r]);
                scale[i] = __expf(m_run[i] - mnew);
                m_run[i] = mnew;
                float p[8];
                float ps = 0.f;
                #pragma unroll
                for (int j = 0; j < 8; ++j) {
                    p[j] = __expf(S[i][j] - mnew);
                    ps += p[j];
                }
                #pragma unroll
                for (int c = 0; c < 3; ++c) {
                    float a = 0.f;
                    #pragma unroll
                    for (int j = 0; j < 8; ++j) a += p[j] * pt[j][c];
                    pv[i][c] = pv[i][c] * scale[i] + a;
                }
                ps += __shfl_xor(ps, 8);
                ps += __shfl_xor(ps, 16);
                ps += __shfl_xor(ps, 32);
                psum[i] = ps;
            }
            if (lane < 8) {
                #pragma unroll
                for (int i = 0; i < 8; ++i) wred[wave][lane * 8 + i] = psum[i];
            }
            __syncthreads();
            if (t < ROWS) {
                float s0 = wred[0][t];
                #pragma unroll
                for (int w = 1; w < 8; ++w) s0 += wred[w][t];
                rowred[t] = s0;
            }
            __syncthreads();
            #pragma unroll
            for (int i = 0; i < 8; ++i)
                l_run[i] = l_run[i] * scale[i] + rowred[rg * 8 + i];
        }

        __syncthreads();  // everyone done reading Ks / PTs
        if (have_next) {
            #pragma unroll
            for (int c = 0; c < 8; ++c) *(float4*)&Ks[t][4 * c] = nv[c];
            if (((s + 1) & 7) == 0) {
                PTs[0][t] = npt[0]; PTs[1][t] = npt[1]; PTs[2][t] = npt[2];
            }
        }
        __syncthreads();
    }

    // ---------------- final reduction: pv across 64 threads sharing rg ----------------
    #pragma unroll
    for (int i = 0; i < 8; ++i)
        #pragma unroll
        for (int c = 0; c < 3; ++c) {
            float v = pv[i][c];
            v += __shfl_xor(v, 8);
            v += __shfl_xor(v, 16);
            v += __shfl_xor(v, 32);
            pv[i][c] = v;
        }
    if (lane < 8) {
        #pragma unroll
        for (int i = 0; i < 8; ++i)
            #pragma unroll
            for (int c = 0; c < 3; ++c)
                fred[wave][lane][i * 3 + c] = pv[i][c];
        if (wave == 0) {
            #pragma unroll
            for (int i = 0; i < 8; ++i) lrun_s[lane * 8 + i] = l_run[i];
        }
    }
    __syncthreads();

    if (t < ROWS) {
        const int trg = t >> 3, ti = t & 7;
        float pc[3];
        #pragma unroll
        for (int c = 0; c < 3; ++c) {
            float v = 0.f;
            #pragma unroll
            for (int w = 0; w < 8; ++w) v += fred[w][trg][ti * 3 + c];
            pc[c] = v / lrun_s[t];
        }
        const float* ps = p_src + ((size_t)b * NQ + row0 + t) * 3;
        const float sp0 = ps[0], sp1 = ps[1], sp2 = ps[2];
        float vals[15];
        vals[0] = sp0; vals[1] = sp1; vals[2] = sp2;
        vals[3] = pc[0]; vals[4] = pc[1]; vals[5] = pc[2];
        vals[6]  = sp0 * pc[0]; vals[7]  = sp0 * pc[1]; vals[8]  = sp0 * pc[2];
        vals[9]  = sp1 * pc[0]; vals[10] = sp1 * pc[1]; vals[11] = sp1 * pc[2];
        vals[12] = sp2 * pc[0]; vals[13] = sp2 * pc[1]; vals[14] = sp2 * pc[2];
        #pragma unroll
        for (int k2 = 0; k2 < 15; ++k2) {
            float v = vals[k2];
            #pragma unroll
            for (int d = 1; d < 64; d <<= 1) v += __shfl_xor(v, d);
            vals[k2] = v;
        }
        if (t == 0) {
            #pragma unroll
            for (int k2 = 0; k2 < 15; ++k2)
                atomicAdd(&out_acc[b * 16 + k2], vals[k2]);
        }
    }
}

// ---------------------------------------------------------------------------
// Per-batch 3x3 Kabsch: H from accumulated sums, fp64 Jacobi SVD, writes 4x4.
// Reads accumulators from out[b*16+0..14], overwrites out[b*16+0..15].
// ---------------------------------------------------------------------------
__global__ void svd_kernel(float* __restrict__ out)
{
    const int b = threadIdx.x;
    if (b >= NB) return;

    float sbuf[15];
    #pragma unroll
    for (int i = 0; i < 15; ++i) sbuf[i] = out[b * 16 + i];

    const double invN = 1.0 / (double)NQ;
    double Sp[3] = {sbuf[0], sbuf[1], sbuf[2]};
    double Sc[3] = {sbuf[3], sbuf[4], sbuf[5]};
    double H[3][3];
    for (int i = 0; i < 3; ++i)
        for (int j = 0; j < 3; ++j)
            H[i][j] = (double)sbuf[6 + i * 3 + j] - Sp[i] * Sc[j] * invN;
    double cs[3], cc[3];
    for (int i = 0; i < 3; ++i) { cs[i] = Sp[i] * invN; cc[i] = Sc[i] * invN; }

    // A = H^T H (symmetric), Jacobi eigendecomposition -> V, lambda
    double A[3][3];
    for (int i = 0; i < 3; ++i)
        for (int j = 0; j < 3; ++j)
            A[i][j] = H[0][i]*H[0][j] + H[1][i]*H[1][j] + H[2][i]*H[2][j];
    double V[3][3] = {{1,0,0},{0,1,0},{0,0,1}};

    for (int sweep = 0; sweep < 30; ++sweep) {
        for (int pp = 0; pp < 3; ++pp) {
            const int p = (pp == 2) ? 1 : 0;
            const int q = (pp == 0) ? 1 : 2;
            const double apq = A[p][q];
            if (fabs(apq) < 1e-300) continue;
            const double app = A[p][p], aqq = A[q][q];
            const double tau = (aqq - app) / (2.0 * apq);
            const double tt  = (tau >= 0.0 ? 1.0 : -1.0) /
                               (fabs(tau) + sqrt(1.0 + tau * tau));
            const double c  = 1.0 / sqrt(1.0 + tt * tt);
            const double sn = tt * c;
            const int r = 3 - p - q;
            const double arp = A[r][p], arq = A[r][q];
            A[p][p] = app - tt * apq;
            A[q][q] = aqq + tt * apq;
            A[p][q] = A[q][p] = 0.0;
            A[r][p] = A[p][r] = c * arp - sn * arq;
            A[r][q] = A[q][r] = sn * arp + c * arq;
            for (int i = 0; i < 3; ++i) {
                const double vip = V[i][p], viq = V[i][q];
                V[i][p] = c * vip - sn * viq;
                V[i][q] = sn * vip + c * viq;
            }
        }
    }

    // sort eigenpairs descending
    int idx[3] = {0, 1, 2};
    double lam[3] = {A[0][0], A[1][1], A[2][2]};
    if (lam[idx[0]] < lam[idx[1]]) { int u = idx[0]; idx[0] = idx[1]; idx[1] = u; }
    if (lam[idx[0]] < lam[idx[2]]) { int u = idx[0]; idx[0] = idx[2]; idx[2] = u; }
    if (lam[idx[1]] < lam[idx[2]]) { int u = idx[1]; idx[1] = idx[2]; idx[2] = u; }

    double Vs[3][3], sv[3];
    for (int k = 0; k < 3; ++k) {
        for (int i = 0; i < 3; ++i) Vs[i][k] = V[i][idx[k]];
        const double l2 = lam[idx[k]];
        sv[k] = (l2 > 0.0) ? sqrt(l2) : 0.0;
    }

    // U columns: u_k = H v_k / s_k  (cross-product fallback for tiny s2)
    double U[3][3];
    for (int k = 0; k < 3; ++k) {
        double u0 = H[0][0]*Vs[0][k] + H[0][1]*Vs[1][k] + H[0][2]*Vs[2][k];
        double u1 = H[1][0]*Vs[0][k] + H[1][1]*Vs[1][k] + H[1][2]*Vs[2][k];
        double u2 = H[2][0]*Vs[0][k] + H[2][1]*Vs[1][k] + H[2][2]*Vs[2][k];
        double nn = sqrt(u0*u0 + u1*u1 + u2*u2);
        if (k == 2 && (sv[2] <= 1e-10 * sv[0] || nn == 0.0)) {
            u0 = U[1][0]*U[2][1] - U[2][0]*U[1][1];
            u1 = U[2][0]*U[0][1] - U[0][0]*U[2][1];
            u2 = U[0][0]*U[1][1] - U[1][0]*U[0][1];
            nn = sqrt(u0*u0 + u1*u1 + u2*u2);
        }
        const double inv = (nn > 0.0) ? 1.0 / nn : 0.0;
        U[0][k] = u0 * inv; U[1][k] = u1 * inv; U[2][k] = u2 * inv;
    }

    // R = Vs U^T; det<0 -> flip third (smallest-sigma) column of Vs
    double R[3][3];
    for (int i = 0; i < 3; ++i)
        for (int j = 0; j < 3; ++j)
            R[i][j] = Vs[i][0]*U[j][0] + Vs[i][1]*U[j][1] + Vs[i][2]*U[j][2];
    const double det =
          R[0][0]*(R[1][1]*R[2][2] - R[1][2]*R[2][1])
        - R[0][1]*(R[1][0]*R[2][2] - R[1][2]*R[2][0])
        + R[0][2]*(R[1][0]*R[2][1] - R[1][1]*R[2][0]);
    if (det < 0.0)
        for (int i = 0; i < 3; ++i)
            for (int j = 0; j < 3; ++j)
                R[i][j] -= 2.0 * Vs[i][2] * U[j][2];

    double tv[3];
    for (int i = 0; i < 3; ++i)
        tv[i] = cc[i] - (R[i][0]*cs[0] + R[i][1]*cs[1] + R[i][2]*cs[2]);

    for (int i = 0; i < 3; ++i) {
        for (int j = 0; j < 3; ++j) out[b*16 + i*4 + j] = (float)R[i][j];
        out[b*16 + i*4 + 3] = (float)tv[i];
    }
    out[b*16 + 12] = 0.f; out[b*16 + 13] = 0.f;
    out[b*16 + 14] = 0.f; out[b*16 + 15] = 1.f;
}

extern "C" void kernel_launch(void* const* d_in, const int* in_sizes, int n_in,
                              void* d_out, int out_size, void* d_ws, size_t ws_size,
                              hipStream_t stream)
{
    const float* p_src = (const float*)d_in[0];
    const float* f_src = (const float*)d_in[1];
    const float* p_tgt = (const float*)d_in[2];
    const float* f_tgt = (const float*)d_in[3];
    const float* W     = (const float*)d_in[4];
    const float* bias  = (const float*)d_in[5];
    float* out = (float*)d_out;

    // accumulators live in d_out[b*16 + 0..14]; zero them (d_out is poisoned)
    hipMemsetAsync(out, 0, 64 * sizeof(float), stream);

    dim3 grid(NQ / ROWS, NB);   // (64, 4) = 256 blocks
    flash_kernel<<<grid, NTHR, 0, stream>>>(p_src, f_src, p_tgt, f_tgt, W, bias, out);
    svd_kernel<<<1, 64, 0, stream>>>(out);
}